// Round 1
// baseline (113.953 us; speedup 1.0000x reference)
//
#include <hip/hip_runtime.h>
#include <stdint.h>

// Fused Swin window attention for MI355X (gfx950).
// B=4096 windows, N=64 tokens, C=128, H=4 heads, D=32, WS=8.
// One block = one window; 4 waves = 4 heads; bf16 MFMA 16x16x32, f32 accum.
// LDS (64KB static):
//   region A [0,16K):   x staged bf16 [64][256B] swizzled; later O bf16 (same layout)
//   region B [16K,48K): per-head Q(4K)+K(4K); aliased by P (8K/head); aliased by
//                       f32 out-staging [64][512B] slot-swizzled
//   region C [48K,64K): per-head Vt [32][128B] (d-major, key-contiguous)
// Weights pre-packed into d_ws in exact B-fragment order by prep_kernel:
//   wq bf16 @0 (96KB), wp bf16 @98304 (32KB), bias_full f32 [H][64][64] @131072 (64KB)

typedef __attribute__((ext_vector_type(4))) float  f32x4;
typedef __attribute__((ext_vector_type(8))) __bf16 bf16x8;

#define DEV static __device__ __forceinline__

DEV unsigned short f2bf(float f) {          // f32 -> bf16 RNE
  unsigned int u = __float_as_uint(f);
  u += 0x7FFFu + ((u >> 16) & 1u);
  return (unsigned short)(u >> 16);
}

// Swizzled LDS byte-address helpers. cb = pre-swizzle byte offset within row.
// All XOR values are multiples of 16 -> preserve <=16B alignment; writer and
// reader share the same function so correctness is layout-independent.
DEV int xaddr (int r, int cb) { return r*256 + (cb ^ ((r & 7) << 4)); }        // 256B rows (x / O)
DEV int qkaddr(int r, int cb) { return r*64  + (cb ^ (((r >> 1) & 3) << 4)); } // 64B rows (Q, K)
DEV int vtaddr(int d, int cb) { return d*128 + (cb ^ ((d & 7) << 4)); }        // 128B rows (Vt)
DEV int paddr (int r, int cb) { return r*128 + (cb ^ ((r & 7) << 4)); }        // 128B rows (P)
DEV int staddr(int r, int cb) { return r*512 + (cb ^ ((r & 15) << 4)); }       // 512B rows (f32 staging)

template <int CTRL>
DEV float dppf(float v) {
  return __int_as_float(__builtin_amdgcn_mov_dpp(__float_as_int(v), CTRL, 0xF, 0xF, false));
}
// 16-lane (DPP row) reduction via row_ror 8/4/2/1 — pure VALU, no LDS traffic.
DEV float rmax16(float v) {
  v = fmaxf(v, dppf<0x128>(v)); v = fmaxf(v, dppf<0x124>(v));
  v = fmaxf(v, dppf<0x122>(v)); v = fmaxf(v, dppf<0x121>(v));
  return v;
}
DEV float rsum16(float v) {
  v += dppf<0x128>(v); v += dppf<0x124>(v); v += dppf<0x122>(v); v += dppf<0x121>(v);
  return v;
}

DEV f32x4 mfma16(bf16x8 a, bf16x8 b, f32x4 c) {
  return __builtin_amdgcn_mfma_f32_16x16x32_bf16(a, b, c, 0, 0, 0);
}

// Pre-pack weights into B-fragment order and expand the relative-position bias.
// B-frag for 16x16x32: lane l holds B[k=(ks*32+(l>>4)*8+i)][col=nt*16+(l&15)], i=0..7.
// Packed element index: ((nt*4+ks)*64 + lane)*8 + i  -> lane reads contiguous 16B.
__global__ void prep_kernel(const float* __restrict__ qkv_w, const float* __restrict__ proj_w,
                            const float* __restrict__ bias_table,
                            unsigned short* __restrict__ wq, unsigned short* __restrict__ wp,
                            float* __restrict__ bias_full) {
  int idx = blockIdx.x * 256 + threadIdx.x;
  if (idx < 49152) {                                    // qkv_w (128 x 384)
    int i = idx & 7, lane = (idx >> 3) & 63, ks = (idx >> 9) & 3, nt = idx >> 11;
    int k = ks*32 + (lane >> 4)*8 + i;
    int col = nt*16 + (lane & 15);
    wq[idx] = f2bf(qkv_w[k*384 + col]);
  } else if (idx < 65536) {                             // proj_w (128 x 128)
    int t = idx - 49152;
    int i = t & 7, lane = (t >> 3) & 63, ks = (t >> 9) & 3, nt = t >> 11;
    int k = ks*32 + (lane >> 4)*8 + i;
    int col = nt*16 + (lane & 15);
    wp[t] = f2bf(proj_w[k*128 + col]);
  } else if (idx < 81920) {                             // bias_full[h][q][k]
    int t = idx - 65536;
    int h = t >> 12, q = (t >> 6) & 63, kk = t & 63;
    int ri = q >> 3, ci = q & 7, rj = kk >> 3, cj = kk & 7;
    bias_full[t] = bias_table[((ri - rj + 7)*15 + (ci - cj + 7))*4 + h];
  }
}

__global__ __launch_bounds__(256, 2) void fused_kernel(
    const float* __restrict__ x, const float* __restrict__ qkv_b, const float* __restrict__ proj_b,
    const unsigned short* __restrict__ wq, const unsigned short* __restrict__ wp,
    const float* __restrict__ bias_full, float* __restrict__ out)
{
  __shared__ __align__(16) char lds[65536];
  const int b    = blockIdx.x;
  const int tid  = threadIdx.x;
  const int lane = tid & 63;
  const int w    = tid >> 6;       // wave id == head id
  const int l15  = lane & 15;
  const int lq   = lane >> 4;      // quarter-wave 0..3
  const float SCALE = 0.17677669529663687f;   // D^-0.5
  const f32x4 FZ = {0.f, 0.f, 0.f, 0.f};

  // ---------- Phase 0: stage x -> region A as bf16 (swizzled) ----------
  {
    const float4* x4 = (const float4*)(x + (size_t)b * 8192);
    #pragma unroll
    for (int it = 0; it < 8; ++it) {
      int f4 = it*256 + tid;                 // 0..2047
      int r = f4 >> 5, c4 = f4 & 31;
      float4 v = x4[f4];
      unsigned int lo = (unsigned int)f2bf(v.x) | ((unsigned int)f2bf(v.y) << 16);
      unsigned int hi = (unsigned int)f2bf(v.z) | ((unsigned int)f2bf(v.w) << 16);
      *(uint2*)(lds + xaddr(r, c4*8)) = make_uint2(lo, hi);
    }
  }
  __syncthreads();

  // ---------- Phase 1: QKV GEMM (wave computes its own head's Q,K,V) ----------
  // packed n-tiles for head w: Q {2w,2w+1}, K {8+2w,8+2w+1}, V {16+2w,16+2w+1}
  f32x4 acc[6][4];
  #pragma unroll
  for (int t = 0; t < 6; ++t)
    #pragma unroll
    for (int m = 0; m < 4; ++m) acc[t][m] = FZ;

  #pragma unroll
  for (int ks = 0; ks < 4; ++ks) {
    bf16x8 afr[4];
    #pragma unroll
    for (int m = 0; m < 4; ++m)
      afr[m] = *(const bf16x8*)(lds + xaddr(m*16 + l15, ks*64 + lq*16));
    #pragma unroll
    for (int t = 0; t < 6; ++t) {
      int nt = (t >> 1)*8 + 2*w + (t & 1);
      bf16x8 bfr = *(const bf16x8*)((const char*)wq + (nt*4 + ks)*1024 + lane*16);
      #pragma unroll
      for (int m = 0; m < 4; ++m)
        acc[t][m] = mfma16(afr[m], bfr, acc[t][m]);
    }
  }
  __syncthreads();   // all waves done reading region A (x); O may overwrite it later

  char* qb = lds + 16384 + w*8192;   // Q [64][64B]
  char* kb = qb + 4096;              // K [64][64B]
  char* vb = lds + 49152 + w*4096;   // Vt [32][128B]
  #pragma unroll
  for (int t = 0; t < 2; ++t) {
    float bq = qkv_b[       (2*w + t)*16 + l15];
    float bk = qkv_b[128 + (2*w + t)*16 + l15];
    float bv = qkv_b[256 + (2*w + t)*16 + l15];
    #pragma unroll
    for (int m = 0; m < 4; ++m) {
      #pragma unroll
      for (int j = 0; j < 4; ++j) {
        int r = m*16 + lq*4 + j;   // C/D layout: row=(l>>4)*4+reg, col=l&15
        *(unsigned short*)(qb + qkaddr(r, (t*16 + l15)*2)) = f2bf((acc[t  ][m][j] + bq) * SCALE);
        *(unsigned short*)(kb + qkaddr(r, (t*16 + l15)*2)) = f2bf( acc[t+2][m][j] + bk);
      }
      // V written transposed: Vt[d][key], 4 consecutive keys pack into one b64
      int d  = t*16 + l15;
      int r0 = m*16 + lq*4;
      unsigned int lo = (unsigned int)f2bf(acc[t+4][m][0] + bv) | ((unsigned int)f2bf(acc[t+4][m][1] + bv) << 16);
      unsigned int hi = (unsigned int)f2bf(acc[t+4][m][2] + bv) | ((unsigned int)f2bf(acc[t+4][m][3] + bv) << 16);
      *(uint2*)(vb + vtaddr(d, r0*2)) = make_uint2(lo, hi);
    }
  }

  // ---------- Phase 2: attention (entirely wave-local, head w) ----------
  bf16x8 aq[4], bk8[4];
  #pragma unroll
  for (int m = 0; m < 4; ++m) {
    aq [m] = *(const bf16x8*)(qb + qkaddr(m*16 + l15, lq*16));  // A: Q[q][d]
    bk8[m] = *(const bf16x8*)(kb + qkaddr(m*16 + l15, lq*16));  // B: K^T[d][key]=K[key][d]
  }
  f32x4 s[4][4];
  #pragma unroll
  for (int m = 0; m < 4; ++m)
    #pragma unroll
    for (int n = 0; n < 4; ++n)
      s[m][n] = mfma16(aq[m], bk8[n], FZ);

  const float* bh = bias_full + w*4096;
  #pragma unroll
  for (int m = 0; m < 4; ++m)
    #pragma unroll
    for (int j = 0; j < 4; ++j) {
      int q = m*16 + lq*4 + j;
      #pragma unroll
      for (int n = 0; n < 4; ++n)
        s[m][n][j] += bh[q*64 + n*16 + l15];
    }

  // Row softmax; keep P unnormalized, defer 1/sum to the O rescale (inv lands
  // in exactly the right lanes because PV output has the same C/D row layout).
  float inv[4][4];
  #pragma unroll
  for (int m = 0; m < 4; ++m)
    #pragma unroll
    for (int j = 0; j < 4; ++j) {
      float mx = fmaxf(fmaxf(s[m][0][j], s[m][1][j]), fmaxf(s[m][2][j], s[m][3][j]));
      mx = rmax16(mx);
      float sum = 0.f;
      #pragma unroll
      for (int n = 0; n < 4; ++n) {
        float p = __expf(s[m][n][j] - mx);
        s[m][n][j] = p;
        sum += p;
      }
      sum = rsum16(sum);
      inv[m][j] = __fdividef(1.f, sum);
    }

  // P -> LDS bf16 (aliases dead Q+K region; same wave, so just program order)
  char* pb = qb;
  #pragma unroll
  for (int m = 0; m < 4; ++m)
    #pragma unroll
    for (int n = 0; n < 4; ++n)
      #pragma unroll
      for (int j = 0; j < 4; ++j) {
        int q = m*16 + lq*4 + j;
        *(unsigned short*)(pb + paddr(q, (n*16 + l15)*2)) = f2bf(s[m][n][j]);
      }

  // O = P @ V
  f32x4 o[4][2];
  #pragma unroll
  for (int m = 0; m < 4; ++m) { o[m][0] = FZ; o[m][1] = FZ; }
  #pragma unroll
  for (int ks = 0; ks < 2; ++ks) {
    bf16x8 ap[4], bv8[2];
    #pragma unroll
    for (int m = 0; m < 4; ++m)
      ap[m] = *(const bf16x8*)(pb + paddr(m*16 + l15, ks*64 + lq*16));
    #pragma unroll
    for (int n2 = 0; n2 < 2; ++n2)
      bv8[n2] = *(const bf16x8*)(vb + vtaddr(n2*16 + l15, ks*64 + lq*16));
    #pragma unroll
    for (int m = 0; m < 4; ++m)
      #pragma unroll
      for (int n2 = 0; n2 < 2; ++n2)
        o[m][n2] = mfma16(ap[m], bv8[n2], o[m][n2]);
  }

  // rescale + write O (bf16) into region A at column offset w*32
  #pragma unroll
  for (int m = 0; m < 4; ++m)
    #pragma unroll
    for (int n2 = 0; n2 < 2; ++n2)
      #pragma unroll
      for (int j = 0; j < 4; ++j) {
        int r = m*16 + lq*4 + j;
        int c = w*32 + n2*16 + l15;
        *(unsigned short*)(lds + xaddr(r, c*2)) = f2bf(o[m][n2][j] * inv[m][j]);
      }
  __syncthreads();   // O complete; P regions dead -> staging may overwrite region B

  // ---------- Phase 3: output projection (wave w -> out cols 32w..32w+31) ----------
  f32x4 pacc[4][2];
  #pragma unroll
  for (int m = 0; m < 4; ++m) { pacc[m][0] = FZ; pacc[m][1] = FZ; }
  #pragma unroll
  for (int ks = 0; ks < 4; ++ks) {
    bf16x8 ao[4];
    #pragma unroll
    for (int m = 0; m < 4; ++m)
      ao[m] = *(const bf16x8*)(lds + xaddr(m*16 + l15, ks*64 + lq*16));
    #pragma unroll
    for (int t = 0; t < 2; ++t) {
      int nt = 2*w + t;
      bf16x8 bfr = *(const bf16x8*)((const char*)wp + (nt*4 + ks)*1024 + lane*16);
      #pragma unroll
      for (int m = 0; m < 4; ++m)
        pacc[m][t] = mfma16(ao[m], bfr, pacc[m][t]);
    }
  }

  float pb0 = proj_b[(2*w    )*16 + l15];
  float pb1 = proj_b[(2*w + 1)*16 + l15];
  #pragma unroll
  for (int m = 0; m < 4; ++m)
    #pragma unroll
    for (int t = 0; t < 2; ++t)
      #pragma unroll
      for (int j = 0; j < 4; ++j) {
        int r = m*16 + lq*4 + j;
        int c = (2*w + t)*16 + l15;
        *(float*)(lds + 16384 + staddr(r, c*4)) = pacc[m][t][j] + (t ? pb1 : pb0);
      }
  __syncthreads();

  // ---------- Phase 4: coalesced float4 store ----------
  float4* out4 = (float4*)(out + (size_t)b * 8192);
  #pragma unroll
  for (int it = 0; it < 8; ++it) {
    int f4 = it*256 + tid;
    int r = f4 >> 5, c4 = f4 & 31;
    out4[f4] = *(const float4*)(lds + 16384 + staddr(r, c4*16));
  }
}

extern "C" void kernel_launch(void* const* d_in, const int* in_sizes, int n_in,
                              void* d_out, int out_size, void* d_ws, size_t ws_size,
                              hipStream_t stream) {
  const float* x        = (const float*)d_in[0];
  const float* qkv_w    = (const float*)d_in[1];
  const float* qkv_b    = (const float*)d_in[2];
  const float* proj_w   = (const float*)d_in[3];
  const float* proj_b   = (const float*)d_in[4];
  const float* bias_tab = (const float*)d_in[5];
  float* out = (float*)d_out;

  // workspace layout (needs 192 KB): wq bf16 | wp bf16 | bias_full f32
  unsigned short* wq = (unsigned short*)d_ws;
  unsigned short* wp = (unsigned short*)((char*)d_ws + 98304);
  float* bias_full   = (float*)((char*)d_ws + 131072);

  int B = in_sizes[0] / 8192;   // (B, 64, 128)

  prep_kernel<<<320, 256, 0, stream>>>(qkv_w, proj_w, bias_tab, wq, wp, bias_full);
  fused_kernel<<<B, 256, 0, stream>>>(x, qkv_b, proj_b, wq, wp, bias_full, out);
}